// Round 8
// baseline (338265.161 us; speedup 1.0000x reference)
//
#include <hip/hip_runtime.h>
#include <cstdint>
#include <cmath>

typedef unsigned short u16;
typedef unsigned long long u64;
typedef __attribute__((ext_vector_type(8))) short short8;
typedef __attribute__((ext_vector_type(4))) float f32x4;

#define SEQ 1024
#define HD 1024
#define GD 4096
#define NB 8
#define MROWS 8192   // NB*SEQ

__device__ __forceinline__ u16 f2bf(float f) {
  union { float f; uint32_t u; } c; c.f = f;
  uint32_t u = c.u;
  uint32_t r = (u + 0x7fffu + ((u >> 16) & 1u)) >> 16;
  return (u16)r;
}
__device__ __forceinline__ float bf2f(u16 h) {
  union { uint32_t u; float f; } c; c.u = ((uint32_t)h) << 16;
  return c.f;
}
__device__ __forceinline__ u64 load_sc0(const u64* p) {
  u64 v;
  asm volatile("global_load_dwordx2 %0, %1, off sc0\n\ts_waitcnt vmcnt(0)"
               : "=v"(v) : "v"((u64)(uintptr_t)p) : "memory");
  return v;
}
__device__ __forceinline__ void store_sc0(u64* p, u64 v) {
  asm volatile("global_store_dwordx2 %0, %1, off sc0"
               :: "v"((u64)(uintptr_t)p), "v"(v) : "memory");
}

// ---------------- fp32 -> bf16 convert ----------------
__global__ void k_tobf16(const float* __restrict__ in, u16* __restrict__ out, long n) {
  long i = ((long)blockIdx.x * 256L + threadIdx.x) * 4;
  long st = (long)gridDim.x * 1024L;
  for (; i < n; i += st) {
    float4 v = *(const float4*)(in + i);
    ushort4 o;
    o.x = f2bf(v.x); o.y = f2bf(v.y); o.z = f2bf(v.z); o.w = f2bf(v.w);
    *(ushort4*)(out + i) = o;
  }
}

// ---------------- bf16 MFMA GEMM: C[m][n] = sum_k A[m][k]*Bw[n][k] (+epilogue) ----
template<int MODE>
__global__ __launch_bounds__(256, 1) void k_gemm(
    const u16* __restrict__ A, const u16* __restrict__ Bw,
    const float* __restrict__ bias, const float* __restrict__ res,
    u16* __restrict__ outb, float* __restrict__ outf, int N, int K)
{
  __shared__ u16 As[128][40];
  __shared__ u16 Bs[128][40];
  const int tid = threadIdx.x;
  const int wid = tid >> 6, lane = tid & 63;
  const int wm = wid >> 1, wn = wid & 1;
  const int r = lane & 15, q = lane >> 4;
  const long m0 = (long)blockIdx.y * 128, n0 = (long)blockIdx.x * 128;
  const int srow = tid >> 1, sseg = (tid & 1) * 16;

  f32x4 acc[4][4];
#pragma unroll
  for (int i = 0; i < 4; ++i)
#pragma unroll
    for (int j = 0; j < 4; ++j) acc[i][j] = (f32x4){0.f, 0.f, 0.f, 0.f};

  const u16* ag = A + (m0 + srow) * (long)K + sseg;
  const u16* bg = Bw + (n0 + srow) * (long)K + sseg;

  for (int k0 = 0; k0 < K; k0 += 32) {
    short8 av0 = *(const short8*)(ag + k0);
    short8 av1 = *(const short8*)(ag + k0 + 8);
    short8 bv0 = *(const short8*)(bg + k0);
    short8 bv1 = *(const short8*)(bg + k0 + 8);
    __syncthreads();
    *(short8*)&As[srow][sseg]     = av0;
    *(short8*)&As[srow][sseg + 8] = av1;
    *(short8*)&Bs[srow][sseg]     = bv0;
    *(short8*)&Bs[srow][sseg + 8] = bv1;
    __syncthreads();
    short8 bfr[4];
#pragma unroll
    for (int ni = 0; ni < 4; ++ni)
      bfr[ni] = *(const short8*)&Bs[wn * 64 + ni * 16 + r][q * 8];
#pragma unroll
    for (int mi = 0; mi < 4; ++mi) {
      short8 afr = *(const short8*)&As[wm * 64 + mi * 16 + r][q * 8];
#pragma unroll
      for (int ni = 0; ni < 4; ++ni)
        acc[mi][ni] = __builtin_amdgcn_mfma_f32_16x16x32_bf16(afr, bfr[ni], acc[mi][ni], 0, 0, 0);
    }
  }

#pragma unroll
  for (int mi = 0; mi < 4; ++mi)
#pragma unroll
    for (int ni = 0; ni < 4; ++ni) {
      long col = n0 + wn * 64 + ni * 16 + r;
      float bc = bias[col];
#pragma unroll
      for (int rr = 0; rr < 4; ++rr) {
        long row = m0 + wm * 64 + mi * 16 + q * 4 + rr;
        float v = acc[mi][ni][rr] + bc;
        if (MODE == 0) {
          long b = row >> 10, t = row & 1023;
          outb[((t * 8 + b) << 12) + col] = f2bf(v);
        } else {
          float ge = 0.5f * v * (1.0f + erff(v * 0.70710678118654752f));
          outf[row * N + col] = ge + res[row * N + col];
        }
      }
    }
}

// ---------------- persistent sLSTM scan: XCD-aware tagged exchange ----------
// 256 WGs x 512 threads, 88KB LDS forces 1 WG/CU -> all 256 CUs filled ->
// batch group b=wgid&7 expected co-XCD (verified at runtime, not assumed).
// Writers publish tagged (tag16|bf16) u64s TWICE: sc0 store (own XCD L2) +
// agent store (MALL backup). Readers poll sc0-local if writer co-XCD (checked
// via HW_REG_XCC_ID table), else agent; spin-cap fallback for safety.
// Weights pinned in VGPRs via opaque asm (128 VGPR/lane).
__global__ __launch_bounds__(512, 1) void k_scan(
    const u16* __restrict__ xp, const u16* __restrict__ Rb,
    u16* __restrict__ hseq, u64* __restrict__ hxL, u64* __restrict__ hxA,
    unsigned* __restrict__ xcdtab, int tagbase)
{
  __shared__ float Dred[2][8][128];   // [par][wave][g*32+u]
  __shared__ u16 xpf[4][4][32];       // [t&3][g][u]
  __shared__ u16 hhist[32][32];       // [t&31][u]
  __shared__ unsigned sh_myx;
  __shared__ unsigned sh_wx[32];      // xcd of each chunk's writer WG
  __shared__ u64 lds_pad[9600];       // 76.8KB pad -> 1 WG/CU

  const int tid = threadIdx.x;
  const int wgid = blockIdx.x;
  const int b = wgid & 7, c = wgid >> 3;
  const int w = tid >> 6, lane = tid & 63;
  const int r = lane & 15, q = lane >> 4;

  if (tagbase < 0) { volatile u64* vp = lds_pad; vp[0] = 1; }  // keep pad alive

  // publish own XCD id; read into shared
  if (tid == 0) {
    unsigned x;
    asm volatile("s_getreg_b32 %0, hwreg(HW_REG_XCC_ID)" : "=s"(x));
    x &= 7u;
    sh_myx = x;
    __hip_atomic_store(&xcdtab[wgid], 0x5A0u | x,
                       __ATOMIC_RELAXED, __HIP_MEMORY_SCOPE_AGENT);
  }

  // ---- weights G2R: wave w holds k in [w*128,(w+1)*128) for 128 local rows.
  short8 wt[8][4];
#pragma unroll
  for (int j = 0; j < 8; ++j) {
    const int coll = j * 16 + r;
    const int g = coll >> 5, u = coll & 31;
    const u16* src = Rb + ((long)(g * HD + c * 32 + u)) * HD + w * 128 + q * 8;
#pragma unroll
    for (int s = 0; s < 4; ++s)
      wt[j][s] = *(const short8*)(src + s * 32);
  }
  // pin weights in VGPRs (opaque def: cannot be rematerialized from memory)
#pragma unroll
  for (int j = 0; j < 8; ++j)
#pragma unroll
    for (int s = 0; s < 4; ++s)
      asm volatile("" : "+v"(wt[j][s]));

  // prologue: xpf[0],xpf[1]  (xp t-major)
  if (w == 0 && lane < 32) {
    const int g = lane >> 3, o4 = (lane & 7) * 4;
#pragma unroll
    for (int t = 0; t < 2; ++t) {
      u64 v = *(const u64*)(xp + ((long)(t * 8 + b) << 12) + g * 1024 + c * 32 + o4);
      *(u64*)&xpf[t][g][o4] = v;
    }
  }
  // gather writer xcds for my batch (writer of chunk k is wgid = k*8 + b)
  if (w == 1 && lane < 32) {
    unsigned v;
    do {
      v = __hip_atomic_load(&xcdtab[lane * 8 + b],
                            __ATOMIC_RELAXED, __HIP_MEMORY_SCOPE_AGENT);
    } while ((v & ~7u) != 0x5A0u);
    sh_wx[lane] = v & 7u;
  }
  __syncthreads();

  const unsigned myx = sh_myx;
  const int cI = w * 4 + (lane >> 4);           // chunk my polled u64 belongs to
  bool uselocal = (sh_wx[cI] == myx);

  float c_s = 0.f, n_s = 0.f, m_s = 0.f;

  for (int i = 0; i < SEQ; ++i) {
    // ---- phase A (all 8 waves): Dred[i&1] = h_{i-1} @ R^T partials
    if (i > 0) {
      const unsigned tg = (unsigned)(tagbase + i - 1) & 0xffffu;
      const long ofs = ((long)(b * 2 + ((i - 1) & 1)) << 9) + (w << 6) + lane;
      u64 hv = 0;
      bool ok = false;
      int spin = 0;
#pragma unroll 1
      while (__any(!ok)) {
        if (!ok) {
          u64 t2 = uselocal ? load_sc0(hxL + ofs)
                            : __hip_atomic_load(hxA + ofs, __ATOMIC_RELAXED,
                                                __HIP_MEMORY_SCOPE_AGENT);
          if ((((unsigned)(t2 >> 16)) & 0xffffu) == tg &&
              ((unsigned)(t2 >> 48)) == tg) { hv = t2; ok = true; }
          else if (++spin > 100000) uselocal = false;   // safety fallback
        }
      }
      unsigned pk = ((unsigned)hv & 0xffffu) | (((unsigned)(hv >> 32) & 0xffffu) << 16);

      f32x4 acc[8];
#pragma unroll
      for (int j = 0; j < 8; ++j) acc[j] = (f32x4){0.f, 0.f, 0.f, 0.f};
#pragma unroll
      for (int s = 0; s < 4; ++s) {
        union { unsigned x[4]; short8 v; } af;
#pragma unroll
        for (int m2 = 0; m2 < 4; ++m2)
          af.x[m2] = __shfl(pk, s * 16 + q * 4 + m2, 64);
#pragma unroll
        for (int j = 0; j < 8; ++j)
          acc[j] = __builtin_amdgcn_mfma_f32_16x16x32_bf16(af.v, wt[j][s], acc[j], 0, 0, 0);
      }
      if (q == 0) {
#pragma unroll
        for (int j = 0; j < 8; ++j)
          Dred[i & 1][w][j * 16 + r] = acc[j][0];      // D row 0
      }
    }
    __syncthreads();

    // ---- phase C: wave 7 = gates + publish; wave 0 = xp prefetch
    if (w == 7) {
      const int u = lane & 31;
      float pre[4];
#pragma unroll
      for (int g = 0; g < 4; ++g) {
        float s2 = bf2f(xpf[i & 3][g][u]);
        if (i > 0) {
#pragma unroll
          for (int w2 = 0; w2 < 8; ++w2) s2 += Dred[i & 1][w2][g * 32 + u];
        }
        pre[g] = s2;
      }
      float mn = fmaxf(pre[1] + m_s, pre[0]);
      float ig = __expf(pre[0] - mn);
      float fg = __expf(pre[1] + m_s - mn);
      float e2 = __expf(2.f * pre[2]);
      float th = 1.f - 2.f / (e2 + 1.f);               // tanh(pre[2])
      c_s = fg * c_s + ig * th;
      n_s = fg * n_s + ig;
      m_s = mn;
      float og = 1.f / (1.f + __expf(-pre[3]));
      float h = og * (c_s / n_s);

      unsigned hu = (unsigned)f2bf(h);
      unsigned word = (((unsigned)(tagbase + i) & 0xffffu) << 16) | hu;
      unsigned wa = __shfl(word, (lane * 2) & 63, 64);
      unsigned wb = __shfl(word, (lane * 2 + 1) & 63, 64);
      if (lane < 16 && i < SEQ - 1) {
        u64 v64 = (u64)wa | ((u64)wb << 32);
        const long o2 = ((long)(b * 2 + (i & 1)) << 9) + (c << 4) + lane;
        store_sc0(hxL + o2, v64);                      // XCD-local fast lane
        __hip_atomic_store(hxA + o2, v64, __ATOMIC_RELAXED,
                           __HIP_MEMORY_SCOPE_AGENT);  // always-correct backup
      }
      // history + amortized hseq dump (off critical path)
      if (lane < 32) {
        hhist[i & 31][lane] = (u16)hu;
        if ((i & 31) == 31) {
#pragma unroll
          for (int j = 0; j < 4; ++j) {
            short8 v = *(const short8*)&hhist[lane][j * 8];
            *(short8*)(hseq + ((long)(b * SEQ + (i - 31 + lane))) * HD + c * 32 + j * 8) = v;
          }
        }
      }
    } else if (w == 0 && lane < 32 && i + 2 < SEQ) {
      const int g = lane >> 3, o4 = (lane & 7) * 4;
      u64 v = *(const u64*)(xp + ((long)((i + 2) * 8 + b) << 12) + g * 1024 + c * 32 + o4);
      *(u64*)&xpf[(i + 2) & 3][g][o4] = v;
    }
    // single barrier/step: next phase-A poll is the inter-WG sync
  }
}

// ---------------- row LayerNorm (D=1024), fp32 out + bf16 copy ----------------
__global__ __launch_bounds__(256, 1) void k_ln(
    const float* __restrict__ z, const float* __restrict__ gamma, const float* __restrict__ beta,
    float* __restrict__ xout, u16* __restrict__ xb)
{
  const int row = blockIdx.x, tid = threadIdx.x;
  const float4 v = *(const float4*)(z + (long)row * HD + tid * 4);
  float s = v.x + v.y + v.z + v.w;
  float s2 = v.x * v.x + v.y * v.y + v.z * v.z + v.w * v.w;
#pragma unroll
  for (int off = 32; off > 0; off >>= 1) {
    s += __shfl_down(s, off, 64);
    s2 += __shfl_down(s2, off, 64);
  }
  __shared__ float red[8];
  const int wid = tid >> 6, lane = tid & 63;
  if (lane == 0) { red[wid] = s; red[4 + wid] = s2; }
  __syncthreads();
  float su = red[0] + red[1] + red[2] + red[3];
  float sq = red[4] + red[5] + red[6] + red[7];
  float mu = su * (1.f / 1024.f);
  float var = sq * (1.f / 1024.f) - mu * mu;
  float rs = rsqrtf(var + 1e-5f);
  const float4 g  = *(const float4*)(gamma + tid * 4);
  const float4 bt = *(const float4*)(beta + tid * 4);
  float4 o;
  o.x = (v.x - mu) * rs * g.x + bt.x;
  o.y = (v.y - mu) * rs * g.y + bt.y;
  o.z = (v.z - mu) * rs * g.z + bt.z;
  o.w = (v.w - mu) * rs * g.w + bt.w;
  *(float4*)(xout + (long)row * HD + tid * 4) = o;
  ushort4 ob;
  ob.x = f2bf(o.x); ob.y = f2bf(o.y); ob.z = f2bf(o.z); ob.w = f2bf(o.w);
  *(ushort4*)(xb + (long)row * HD + tid * 4) = ob;
}

// ---------------- launch ----------------
extern "C" void kernel_launch(void* const* d_in, const int* in_sizes, int n_in,
                              void* d_out, int out_size, void* d_ws, size_t ws_size,
                              hipStream_t stream)
{
  const float* input = (const float*)d_in[0];
  const float* W[2]  = { (const float*)d_in[1], (const float*)d_in[8] };
  const float* R[2]  = { (const float*)d_in[2], (const float*)d_in[9] };
  const float* bb[2] = { (const float*)d_in[3], (const float*)d_in[10] };
  const float* pW[2] = { (const float*)d_in[4], (const float*)d_in[11] };
  const float* pb[2] = { (const float*)d_in[5], (const float*)d_in[12] };
  const float* gm[2] = { (const float*)d_in[6], (const float*)d_in[13] };
  const float* bt[2] = { (const float*)d_in[7], (const float*)d_in[14] };
  float* out = (float*)d_out;

  char* p = (char*)d_ws;
  size_t off = 0;
  auto alloc = [&](size_t bytes) { char* q = p + off; off += (bytes + 255) & ~(size_t)255; return (void*)q; };
  u64* hxL = (u64*)alloc(NB * 2 * 512 * 8);            // 64KB XCD-local tagged
  u64* hxA = (u64*)alloc(NB * 2 * 512 * 8);            // 64KB agent backup
  unsigned* xcdtab = (unsigned*)alloc(2 * 256 * 4);    // per-layer WG->XCD table
  u16* xb     = (u16*)alloc((size_t)MROWS * HD * 2);
  u16* Wb[2]  = { (u16*)alloc((size_t)GD * HD * 2), (u16*)alloc((size_t)GD * HD * 2) };
  u16* Rbv[2] = { (u16*)alloc((size_t)GD * HD * 2), (u16*)alloc((size_t)GD * HD * 2) };
  u16* pWb[2] = { (u16*)alloc((size_t)HD * HD * 2), (u16*)alloc((size_t)HD * HD * 2) };
  u16* xpb    = (u16*)alloc((size_t)MROWS * GD * 2);
  u16* hs     = (u16*)alloc((size_t)MROWS * HD * 2);
  float* zb   = (float*)alloc((size_t)MROWS * HD * 4);
  float* x1   = (float*)alloc((size_t)MROWS * HD * 4);

  auto conv = [&](const float* src, u16* dst, long n) {
    int blocks = (int)((n / 4 + 255) / 256); if (blocks > 2048) blocks = 2048;
    k_tobf16<<<dim3(blocks), dim3(256), 0, stream>>>(src, dst, n);
  };
  conv(input, xb, (long)MROWS * HD);
  conv(W[0], Wb[0], (long)GD * HD);  conv(W[1], Wb[1], (long)GD * HD);
  conv(R[0], Rbv[0], (long)GD * HD); conv(R[1], Rbv[1], (long)GD * HD);
  conv(pW[0], pWb[0], (long)HD * HD); conv(pW[1], pWb[1], (long)HD * HD);

  // per-launch init: poison tagged buffers (0xAAAA never a valid tag), clear table
  hipMemsetAsync(hxL, 0xAA, NB * 2 * 512 * 8, stream);
  hipMemsetAsync(hxA, 0xAA, NB * 2 * 512 * 8, stream);
  hipMemsetAsync(xcdtab, 0, 2 * 256 * 4, stream);

  for (int l = 0; l < 2; ++l) {
    // xp = x @ W.T + b  -> bf16, t-major layout
    k_gemm<0><<<dim3(GD / 128, MROWS / 128), 256, 0, stream>>>(
        xb, Wb[l], bb[l], nullptr, xpb, nullptr, GD, HD);
    // sLSTM scan: 256 WGs x 512 threads, 8 batch groups of 32, XCD-aware
    k_scan<<<dim3(256), dim3(512), 0, stream>>>(
        xpb, Rbv[l], hs, hxL, hxA, xcdtab + l * 256, l * 1024 + 1);
    // z = gelu(hseq @ pW.T + pb) + x_res
    const float* resp = (l == 0) ? input : x1;
    k_gemm<1><<<dim3(HD / 128, MROWS / 128), 256, 0, stream>>>(
        hs, pWb[l], pb[l], resp, nullptr, zb, HD, HD);
    // layernorm -> fp32 x_next (+ bf16 copy for next layer's GEMM1)
    float* xo = (l == 0) ? x1 : out;
    k_ln<<<dim3(MROWS), dim3(256), 0, stream>>>(zb, gm[l], bt[l], xo, xb);
  }
}

// Round 9
// 7343.546 us; speedup vs baseline: 46.0629x; 46.0629x over previous
//
#include <hip/hip_runtime.h>
#include <cstdint>
#include <cmath>

typedef unsigned short u16;
typedef unsigned long long u64;
typedef __attribute__((ext_vector_type(8))) short short8;
typedef __attribute__((ext_vector_type(4))) float f32x4;

#define SEQ 1024
#define HD 1024
#define GD 4096
#define NB 8
#define MROWS 8192   // NB*SEQ
#define NWG 64       // scan WGs; each owns 16 units x all 8 batches

__device__ __forceinline__ u16 f2bf(float f) {
  union { float f; uint32_t u; } c; c.f = f;
  uint32_t u = c.u;
  uint32_t r = (u + 0x7fffu + ((u >> 16) & 1u)) >> 16;
  return (u16)r;
}
__device__ __forceinline__ float bf2f(u16 h) {
  union { uint32_t u; float f; } c; c.u = ((uint32_t)h) << 16;
  return c.f;
}

// ---------------- fp32 -> bf16 convert ----------------
__global__ void k_tobf16(const float* __restrict__ in, u16* __restrict__ out, long n) {
  long i = ((long)blockIdx.x * 256L + threadIdx.x) * 4;
  long st = (long)gridDim.x * 1024L;
  for (; i < n; i += st) {
    float4 v = *(const float4*)(in + i);
    ushort4 o;
    o.x = f2bf(v.x); o.y = f2bf(v.y); o.z = f2bf(v.z); o.w = f2bf(v.w);
    *(ushort4*)(out + i) = o;
  }
}

// ---------------- bf16 MFMA GEMM: C[m][n] = sum_k A[m][k]*Bw[n][k] (+epilogue) ----
// MODE 0: outb[(t*8+b)*4096 + col] = bf16(acc + bias[n])   (t-major for scan)
// MODE 1: outf = gelu(acc + bias[n]) + res[m][n]           (exact gelu)
template<int MODE>
__global__ __launch_bounds__(256, 1) void k_gemm(
    const u16* __restrict__ A, const u16* __restrict__ Bw,
    const float* __restrict__ bias, const float* __restrict__ res,
    u16* __restrict__ outb, float* __restrict__ outf, int N, int K)
{
  __shared__ u16 As[128][40];
  __shared__ u16 Bs[128][40];
  const int tid = threadIdx.x;
  const int wid = tid >> 6, lane = tid & 63;
  const int wm = wid >> 1, wn = wid & 1;
  const int r = lane & 15, q = lane >> 4;
  const long m0 = (long)blockIdx.y * 128, n0 = (long)blockIdx.x * 128;
  const int srow = tid >> 1, sseg = (tid & 1) * 16;

  f32x4 acc[4][4];
#pragma unroll
  for (int i = 0; i < 4; ++i)
#pragma unroll
    for (int j = 0; j < 4; ++j) acc[i][j] = (f32x4){0.f, 0.f, 0.f, 0.f};

  const u16* ag = A + (m0 + srow) * (long)K + sseg;
  const u16* bg = Bw + (n0 + srow) * (long)K + sseg;

  for (int k0 = 0; k0 < K; k0 += 32) {
    short8 av0 = *(const short8*)(ag + k0);
    short8 av1 = *(const short8*)(ag + k0 + 8);
    short8 bv0 = *(const short8*)(bg + k0);
    short8 bv1 = *(const short8*)(bg + k0 + 8);
    __syncthreads();
    *(short8*)&As[srow][sseg]     = av0;
    *(short8*)&As[srow][sseg + 8] = av1;
    *(short8*)&Bs[srow][sseg]     = bv0;
    *(short8*)&Bs[srow][sseg + 8] = bv1;
    __syncthreads();
    short8 bfr[4];
#pragma unroll
    for (int ni = 0; ni < 4; ++ni)
      bfr[ni] = *(const short8*)&Bs[wn * 64 + ni * 16 + r][q * 8];
#pragma unroll
    for (int mi = 0; mi < 4; ++mi) {
      short8 afr = *(const short8*)&As[wm * 64 + mi * 16 + r][q * 8];
#pragma unroll
      for (int ni = 0; ni < 4; ++ni)
        acc[mi][ni] = __builtin_amdgcn_mfma_f32_16x16x32_bf16(afr, bfr[ni], acc[mi][ni], 0, 0, 0);
    }
  }

#pragma unroll
  for (int mi = 0; mi < 4; ++mi)
#pragma unroll
    for (int ni = 0; ni < 4; ++ni) {
      long col = n0 + wn * 64 + ni * 16 + r;
      float bc = bias[col];
#pragma unroll
      for (int rr = 0; rr < 4; ++rr) {
        long row = m0 + wm * 64 + mi * 16 + q * 4 + rr;
        float v = acc[mi][ni][rr] + bc;
        if (MODE == 0) {
          long b = row >> 10, t = row & 1023;
          outb[((t * 8 + b) << 12) + col] = f2bf(v);
        } else {
          float ge = 0.5f * v * (1.0f + erff(v * 0.70710678118654752f));
          outf[row * N + col] = ge + res[row * N + col];
        }
      }
    }
}

// ---------------- persistent sLSTM scan: 64 WGs, batch-rows MFMA ------------
// WG wg owns units U=[wg*16,wg*16+16) for ALL 8 batches. Weights: 64 rows
// (4 gates x 16 units) x 1024 k = 16 short8 = 64 VGPR/lane (register-resident).
// Wave w: k-slice [w*128,(w+1)*128). Per step: poll 16 flags (8 writer WGs x
// 2 halves), direct-load A-frags from hseq (agent u64), 16 MFMAs (batches =
// M rows 0-7), Dred partials. After single barrier: waves 0,1 = gates for
// (b,u) pairs + publish h into hseq (agent stores + vmcnt ack + flag);
// wave 2 = xp prefetch ring.
__global__ __launch_bounds__(512, 1) void k_scan(
    const u16* __restrict__ xp, const u16* __restrict__ Rb,
    u16* __restrict__ hseq, unsigned* __restrict__ flags, int tagbase)
{
  __shared__ float Dred[2][8][4][8][16];   // [par][wave][gate][b][u]
  __shared__ u16 xpf[4][8][4][16];         // [t&3][b][g][u]

  const int tid = threadIdx.x;
  const int wg = blockIdx.x;
  const int w = tid >> 6, lane = tid & 63;
  const int r = lane & 15, q = lane >> 4;

  // ---- weights G2R: wt[ct][kk] = R[ct*1024 + wg*16 + r][w*128 + kk*32 + q*8 ..]
  short8 wt[4][4];
#pragma unroll
  for (int ct = 0; ct < 4; ++ct)
#pragma unroll
    for (int kk = 0; kk < 4; ++kk)
      wt[ct][kk] = *(const short8*)(Rb + ((long)(ct * HD + wg * 16 + r)) * HD
                                    + w * 128 + kk * 32 + q * 8);
#pragma unroll
  for (int ct = 0; ct < 4; ++ct)
#pragma unroll
    for (int kk = 0; kk < 4; ++kk)
      asm volatile("" : "+v"(wt[ct][kk]));

  // prologue: xpf[0],xpf[1]  (xp t-major: ((t*8+b)<<12) + g*1024 + wg*16)
  if (w == 2) {
    const int b = lane >> 3, g = (lane >> 1) & 3, hf = lane & 1;
#pragma unroll
    for (int t = 0; t < 2; ++t) {
      short8 v = *(const short8*)(xp + ((long)(t * 8 + b) << 12) + g * HD + wg * 16 + hf * 8);
      *(short8*)&xpf[t][b][g][hf * 8] = v;
    }
  }
  __syncthreads();

  float c_s = 0.f, n_s = 0.f, m_s = 0.f;

  for (int i = 0; i < SEQ; ++i) {
    // ---- phase A (all 8 waves): Dred[i&1] = h_{i-1} @ R^T partials
    if (i > 0) {
      const unsigned tgt = (unsigned)(tagbase + i);
      bool rdy = (lane >= 16);
#pragma unroll 1
      while (!__all(rdy)) {
        if (!rdy) {
          unsigned v = __hip_atomic_load(
              &flags[((w * 8 + (lane >> 1)) * 2 + (lane & 1)) * 16],
              __ATOMIC_RELAXED, __HIP_MEMORY_SCOPE_AGENT);
          rdy = (v >= tgt);
        }
      }
      asm volatile("" ::: "memory");

      short8 af[4];
      if (r < 8) {
        const u64* hrow = (const u64*)(hseq + (((long)(r * SEQ + (i - 1))) << 10))
                          + (w << 5) + q * 2;
#pragma unroll
        for (int kk = 0; kk < 4; ++kk) {
          union { u64 q2[2]; short8 v; } uu;
          uu.q2[0] = __hip_atomic_load(hrow + kk * 8,     __ATOMIC_RELAXED, __HIP_MEMORY_SCOPE_AGENT);
          uu.q2[1] = __hip_atomic_load(hrow + kk * 8 + 1, __ATOMIC_RELAXED, __HIP_MEMORY_SCOPE_AGENT);
          af[kk] = uu.v;
        }
      } else {
#pragma unroll
        for (int kk = 0; kk < 4; ++kk) af[kk] = (short8){0,0,0,0,0,0,0,0};
      }

      f32x4 acc[4];
#pragma unroll
      for (int ct = 0; ct < 4; ++ct) acc[ct] = (f32x4){0.f, 0.f, 0.f, 0.f};
#pragma unroll
      for (int kk = 0; kk < 4; ++kk)
#pragma unroll
        for (int ct = 0; ct < 4; ++ct)
          acc[ct] = __builtin_amdgcn_mfma_f32_16x16x32_bf16(af[kk], wt[ct][kk], acc[ct], 0, 0, 0);

      if (q < 2) {
#pragma unroll
        for (int ct = 0; ct < 4; ++ct)
#pragma unroll
          for (int rr = 0; rr < 4; ++rr)
            Dred[i & 1][w][ct][q * 4 + rr][r] = acc[ct][rr];   // b = q*4+rr, u = r
      }
    }
    __syncthreads();

    // ---- phase C: waves 0,1 = gates+publish; wave 2 = xp prefetch
    if (w < 2) {
      const int b = w * 4 + (lane >> 4);
      const int u = lane & 15;
      float pre[4];
#pragma unroll
      for (int g = 0; g < 4; ++g) {
        float s2 = bf2f(xpf[i & 3][b][g][u]);
        if (i > 0) {
#pragma unroll
          for (int w2 = 0; w2 < 8; ++w2) s2 += Dred[i & 1][w2][g][b][u];
        }
        pre[g] = s2;
      }
      float mn = fmaxf(pre[1] + m_s, pre[0]);
      float ig = __expf(pre[0] - mn);
      float fg = __expf(pre[1] + m_s - mn);
      float e2 = __expf(2.f * pre[2]);
      float th = 1.f - 2.f / (e2 + 1.f);             // tanh(pre[2])
      c_s = fg * c_s + ig * th;
      n_s = fg * n_s + ig;
      m_s = mn;
      float og = 1.f / (1.f + __expf(-pre[3]));
      float h = og * (c_s / n_s);

      unsigned hu = (unsigned)f2bf(h);
      unsigned lo2 = hu | (__shfl_down(hu, 1) << 16);
      u64 v64 = (u64)lo2 | ((u64)__shfl_down(lo2, 2) << 32);
      if ((lane & 3) == 0) {
        u64* dst = (u64*)(hseq + (((long)(b * SEQ + i)) << 10) + wg * 16 + u);
        __hip_atomic_store(dst, v64, __ATOMIC_RELAXED, __HIP_MEMORY_SCOPE_AGENT);
      }
      asm volatile("s_waitcnt vmcnt(0)" ::: "memory");   // h at coherence point
      if (lane == 0)
        __hip_atomic_store(&flags[(wg * 2 + w) * 16], (unsigned)(tagbase + i + 1),
                           __ATOMIC_RELAXED, __HIP_MEMORY_SCOPE_AGENT);
    } else if (w == 2 && i + 2 < SEQ) {
      const int b = lane >> 3, g = (lane >> 1) & 3, hf = lane & 1;
      short8 v = *(const short8*)(xp + ((long)((i + 2) * 8 + b) << 12) + g * HD + wg * 16 + hf * 8);
      *(short8*)&xpf[(i + 2) & 3][b][g][hf * 8] = v;
    }
    // single barrier per step (top of next iteration's phase A handles sync)
  }
}

// ---------------- row LayerNorm (D=1024), fp32 out + bf16 copy ----------------
__global__ __launch_bounds__(256, 1) void k_ln(
    const float* __restrict__ z, const float* __restrict__ gamma, const float* __restrict__ beta,
    float* __restrict__ xout, u16* __restrict__ xb)
{
  const int row = blockIdx.x, tid = threadIdx.x;
  const float4 v = *(const float4*)(z + (long)row * HD + tid * 4);
  float s = v.x + v.y + v.z + v.w;
  float s2 = v.x * v.x + v.y * v.y + v.z * v.z + v.w * v.w;
#pragma unroll
  for (int off = 32; off > 0; off >>= 1) {
    s += __shfl_down(s, off, 64);
    s2 += __shfl_down(s2, off, 64);
  }
  __shared__ float red[8];
  const int wid = tid >> 6, lane = tid & 63;
  if (lane == 0) { red[wid] = s; red[4 + wid] = s2; }
  __syncthreads();
  float su = red[0] + red[1] + red[2] + red[3];
  float sq = red[4] + red[5] + red[6] + red[7];
  float mu = su * (1.f / 1024.f);
  float var = sq * (1.f / 1024.f) - mu * mu;
  float rs = rsqrtf(var + 1e-5f);
  const float4 g  = *(const float4*)(gamma + tid * 4);
  const float4 bt = *(const float4*)(beta + tid * 4);
  float4 o;
  o.x = (v.x - mu) * rs * g.x + bt.x;
  o.y = (v.y - mu) * rs * g.y + bt.y;
  o.z = (v.z - mu) * rs * g.z + bt.z;
  o.w = (v.w - mu) * rs * g.w + bt.w;
  *(float4*)(xout + (long)row * HD + tid * 4) = o;
  ushort4 ob;
  ob.x = f2bf(o.x); ob.y = f2bf(o.y); ob.z = f2bf(o.z); ob.w = f2bf(o.w);
  *(ushort4*)(xb + (long)row * HD + tid * 4) = ob;
}

// ---------------- launch ----------------
extern "C" void kernel_launch(void* const* d_in, const int* in_sizes, int n_in,
                              void* d_out, int out_size, void* d_ws, size_t ws_size,
                              hipStream_t stream)
{
  const float* input = (const float*)d_in[0];
  const float* W[2]  = { (const float*)d_in[1], (const float*)d_in[8] };
  const float* R[2]  = { (const float*)d_in[2], (const float*)d_in[9] };
  const float* bb[2] = { (const float*)d_in[3], (const float*)d_in[10] };
  const float* pW[2] = { (const float*)d_in[4], (const float*)d_in[11] };
  const float* pb[2] = { (const float*)d_in[5], (const float*)d_in[12] };
  const float* gm[2] = { (const float*)d_in[6], (const float*)d_in[13] };
  const float* bt[2] = { (const float*)d_in[7], (const float*)d_in[14] };
  float* out = (float*)d_out;

  char* p = (char*)d_ws;
  size_t off = 0;
  auto alloc = [&](size_t bytes) { char* q = p + off; off += (bytes + 255) & ~(size_t)255; return (void*)q; };
  unsigned* flags = (unsigned*)alloc(NWG * 2 * 64);    // 128 flags x 64B pad
  u16* xb     = (u16*)alloc((size_t)MROWS * HD * 2);
  u16* Wb[2]  = { (u16*)alloc((size_t)GD * HD * 2), (u16*)alloc((size_t)GD * HD * 2) };
  u16* Rbv[2] = { (u16*)alloc((size_t)GD * HD * 2), (u16*)alloc((size_t)GD * HD * 2) };
  u16* pWb[2] = { (u16*)alloc((size_t)HD * HD * 2), (u16*)alloc((size_t)HD * HD * 2) };
  u16* xpb    = (u16*)alloc((size_t)MROWS * GD * 2);
  u16* hs     = (u16*)alloc((size_t)MROWS * HD * 2);
  float* zb   = (float*)alloc((size_t)MROWS * HD * 4);
  float* x1   = (float*)alloc((size_t)MROWS * HD * 4);

  auto conv = [&](const float* src, u16* dst, long n) {
    int blocks = (int)((n / 4 + 255) / 256); if (blocks > 2048) blocks = 2048;
    k_tobf16<<<dim3(blocks), dim3(256), 0, stream>>>(src, dst, n);
  };
  conv(input, xb, (long)MROWS * HD);
  conv(W[0], Wb[0], (long)GD * HD);  conv(W[1], Wb[1], (long)GD * HD);
  conv(R[0], Rbv[0], (long)GD * HD); conv(R[1], Rbv[1], (long)GD * HD);
  conv(pW[0], pWb[0], (long)HD * HD); conv(pW[1], pWb[1], (long)HD * HD);

  // reset flags once per launch; tagbase keeps layers disjoint within a launch
  hipMemsetAsync(flags, 0, NWG * 2 * 64, stream);

  for (int l = 0; l < 2; ++l) {
    // xp = x @ W.T + b  -> bf16, t-major layout
    k_gemm<0><<<dim3(GD / 128, MROWS / 128), 256, 0, stream>>>(
        xb, Wb[l], bb[l], nullptr, xpb, nullptr, GD, HD);
    // sLSTM scan: 64 WGs x 512 threads
    k_scan<<<dim3(NWG), dim3(512), 0, stream>>>(xpb, Rbv[l], hs, flags, l * 1024);
    // z = gelu(hseq @ pW.T + pb) + x_res
    const float* resp = (l == 0) ? input : x1;
    k_gemm<1><<<dim3(HD / 128, MROWS / 128), 256, 0, stream>>>(
        hs, pWb[l], pb[l], resp, nullptr, zb, HD, HD);
    // layernorm -> fp32 x_next (+ bf16 copy for next layer's GEMM1)
    float* xo = (l == 0) ? x1 : out;
    k_ln<<<dim3(MROWS), dim3(256), 0, stream>>>(zb, gm[l], bt[l], xo, xb);
  }
}

// Round 11
// 4719.165 us; speedup vs baseline: 71.6790x; 1.5561x over previous
//
#include <hip/hip_runtime.h>
#include <cstdint>
#include <cmath>

typedef unsigned short u16;
typedef unsigned long long u64;
typedef __attribute__((ext_vector_type(8))) short short8;
typedef __attribute__((ext_vector_type(4))) float f32x4;

#define SEQ 1024
#define HD 1024
#define GD 4096
#define NB 8
#define MROWS 8192   // NB*SEQ

__device__ __forceinline__ u16 f2bf(float f) {
  union { float f; uint32_t u; } c; c.f = f;
  uint32_t u = c.u;
  uint32_t r = (u + 0x7fffu + ((u >> 16) & 1u)) >> 16;
  return (u16)r;
}
__device__ __forceinline__ float bf2f(u16 h) {
  union { uint32_t u; float f; } c; c.u = ((uint32_t)h) << 16;
  return c.f;
}

// ---------------- fp32 -> bf16 convert ----------------
__global__ void k_tobf16(const float* __restrict__ in, u16* __restrict__ out, long n) {
  long i = ((long)blockIdx.x * 256L + threadIdx.x) * 4;
  long st = (long)gridDim.x * 1024L;
  for (; i < n; i += st) {
    float4 v = *(const float4*)(in + i);
    ushort4 o;
    o.x = f2bf(v.x); o.y = f2bf(v.y); o.z = f2bf(v.z); o.w = f2bf(v.w);
    *(ushort4*)(out + i) = o;
  }
}

// ---------------- bf16 MFMA GEMM: C[m][n] = sum_k A[m][k]*Bw[n][k] (+epilogue) ----
// MODE 0: outb[(t*8+b)*4096 + col] = bf16(acc + bias[n])   (t-major for scan)
// MODE 1: outf = gelu(acc + bias[n]) + res[m][n]           (exact gelu)
template<int MODE>
__global__ __launch_bounds__(256, 1) void k_gemm(
    const u16* __restrict__ A, const u16* __restrict__ Bw,
    const float* __restrict__ bias, const float* __restrict__ res,
    u16* __restrict__ outb, float* __restrict__ outf, int N, int K)
{
  __shared__ u16 As[128][40];
  __shared__ u16 Bs[128][40];
  const int tid = threadIdx.x;
  const int wid = tid >> 6, lane = tid & 63;
  const int wm = wid >> 1, wn = wid & 1;
  const int r = lane & 15, q = lane >> 4;
  const long m0 = (long)blockIdx.y * 128, n0 = (long)blockIdx.x * 128;
  const int srow = tid >> 1, sseg = (tid & 1) * 16;

  f32x4 acc[4][4];
#pragma unroll
  for (int i = 0; i < 4; ++i)
#pragma unroll
    for (int j = 0; j < 4; ++j) acc[i][j] = (f32x4){0.f, 0.f, 0.f, 0.f};

  const u16* ag = A + (m0 + srow) * (long)K + sseg;
  const u16* bg = Bw + (n0 + srow) * (long)K + sseg;

  for (int k0 = 0; k0 < K; k0 += 32) {
    short8 av0 = *(const short8*)(ag + k0);
    short8 av1 = *(const short8*)(ag + k0 + 8);
    short8 bv0 = *(const short8*)(bg + k0);
    short8 bv1 = *(const short8*)(bg + k0 + 8);
    __syncthreads();
    *(short8*)&As[srow][sseg]     = av0;
    *(short8*)&As[srow][sseg + 8] = av1;
    *(short8*)&Bs[srow][sseg]     = bv0;
    *(short8*)&Bs[srow][sseg + 8] = bv1;
    __syncthreads();
    short8 bfr[4];
#pragma unroll
    for (int ni = 0; ni < 4; ++ni)
      bfr[ni] = *(const short8*)&Bs[wn * 64 + ni * 16 + r][q * 8];
#pragma unroll
    for (int mi = 0; mi < 4; ++mi) {
      short8 afr = *(const short8*)&As[wm * 64 + mi * 16 + r][q * 8];
#pragma unroll
      for (int ni = 0; ni < 4; ++ni)
        acc[mi][ni] = __builtin_amdgcn_mfma_f32_16x16x32_bf16(afr, bfr[ni], acc[mi][ni], 0, 0, 0);
    }
  }

#pragma unroll
  for (int mi = 0; mi < 4; ++mi)
#pragma unroll
    for (int ni = 0; ni < 4; ++ni) {
      long col = n0 + wn * 64 + ni * 16 + r;
      float bc = bias[col];
#pragma unroll
      for (int rr = 0; rr < 4; ++rr) {
        long row = m0 + wm * 64 + mi * 16 + q * 4 + rr;
        float v = acc[mi][ni][rr] + bc;
        if (MODE == 0) {
          long b = row >> 10, t = row & 1023;
          outb[((t * 8 + b) << 12) + col] = f2bf(v);
        } else {
          float ge = 0.5f * v * (1.0f + erff(v * 0.70710678118654752f));
          outf[row * N + col] = ge + res[row * N + col];
        }
      }
    }
}

// ---------------- persistent sLSTM scan (R7 base + tagged exchange) ---------
// 256 WGs x 512 threads (8 waves). b = wgid&7, c = wgid>>3 (units [c*32,c*32+32)
// of batch b). Waves 0-7: weights (k-slice w*128) reg/AGPR-resident; per step
// each lane polls ONE self-validating tagged u64 of h_{i-1} (tag16|bf16 per
// u32, agent relaxed loads - no flags, no acks), builds A-frag via shfl,
// 32 MFMAs, Dred[parity]. Single barrier/step. Wave 7: gates + tagged publish
// (fire-and-forget). Wave 0: xp prefetch. Wave 6: amortized hseq dump (hhist).
__global__ __launch_bounds__(512, 1) void k_scan(
    const u16* __restrict__ xp, const u16* __restrict__ Rb,
    u16* __restrict__ hseq, u64* __restrict__ hx, int tagbase)
{
  __shared__ float Dred[2][8][128];   // [par][wave][g*32+u]
  __shared__ u16 xpf[4][4][32];       // [t&3][g][u]
  __shared__ u16 hhist[2][32][32];    // [bank][t&31][u]

  const int tid = threadIdx.x;
  const int wgid = blockIdx.x;
  const int b = wgid & 7, c = wgid >> 3;
  const int w = tid >> 6, lane = tid & 63;
  const int r = lane & 15, q = lane >> 4;

  // ---- weights: wave w holds k in [w*128,(w+1)*128) for 128 local rows.
  // local row j*16+r -> gate g = (j*16+r)>>5, unit u = (j*16+r)&31.
  short8 wt[8][4];
#pragma unroll
  for (int j = 0; j < 8; ++j) {
    const int coll = j * 16 + r;
    const int g = coll >> 5, u = coll & 31;
    const u16* src = Rb + ((long)(g * HD + c * 32 + u)) * HD + w * 128 + q * 8;
#pragma unroll
    for (int s = 0; s < 4; ++s)
      wt[j][s] = *(const short8*)(src + s * 32);
  }

  // prologue: xpf[0],xpf[1]  (xp t-major: ((t*8+b)<<12) + g*1024 + c*32 + u)
  if (w == 0 && lane < 32) {
    const int g = lane >> 3, o4 = (lane & 7) * 4;
#pragma unroll
    for (int t = 0; t < 2; ++t) {
      u64 v = *(const u64*)(xp + ((long)(t * 8 + b) << 12) + g * 1024 + c * 32 + o4);
      *(u64*)&xpf[t][g][o4] = v;
    }
  }
  __syncthreads();

  float c_s = 0.f, n_s = 0.f, m_s = 0.f;

  for (int i = 0; i < SEQ; ++i) {
    // ---- phase A (all 8 waves): Dred[i&1] = h_{i-1} @ R^T partials
    if (i > 0) {
      // poll own tagged u64 of h_{i-1}: 2 h values per u64, 64 u64 per wave slice
      const unsigned tg = (unsigned)(tagbase + i - 1) & 0xffffu;
      const u64* src = hx + ((long)(b * 2 + ((i - 1) & 1)) << 9) + (w << 6) + lane;
      u64 hv;
#pragma unroll 1
      for (;;) {
        hv = __hip_atomic_load(src, __ATOMIC_RELAXED, __HIP_MEMORY_SCOPE_AGENT);
        if ((((unsigned)(hv >> 16)) & 0xffffu) == tg &&
            ((unsigned)(hv >> 48)) == tg) break;
      }
      unsigned pk = ((unsigned)hv & 0xffffu) | (((unsigned)(hv >> 32) & 0xffffu) << 16);

      f32x4 acc[8];
#pragma unroll
      for (int j = 0; j < 8; ++j) acc[j] = (f32x4){0.f, 0.f, 0.f, 0.f};
#pragma unroll
      for (int s = 0; s < 4; ++s) {
        union { unsigned x[4]; short8 v; } af;
#pragma unroll
        for (int m2 = 0; m2 < 4; ++m2)
          af.x[m2] = __shfl(pk, s * 16 + q * 4 + m2, 64);
#pragma unroll
        for (int j = 0; j < 8; ++j)
          acc[j] = __builtin_amdgcn_mfma_f32_16x16x32_bf16(af.v, wt[j][s], acc[j], 0, 0, 0);
      }
      if (q == 0) {
#pragma unroll
        for (int j = 0; j < 8; ++j)
          Dred[i & 1][w][j * 16 + r] = acc[j][0];      // D row 0 = h slice result
      }
    }
    __syncthreads();

    // ---- phase C: wave 7 = gates + tagged publish; wave 0 = xp prefetch;
    //               wave 6 = amortized hseq dump
    if (w == 7) {
      const int u = lane & 31;
      float pre[4];
#pragma unroll
      for (int g = 0; g < 4; ++g) {
        float s2 = bf2f(xpf[i & 3][g][u]);
        if (i > 0) {
#pragma unroll
          for (int w2 = 0; w2 < 8; ++w2) s2 += Dred[i & 1][w2][g * 32 + u];
        }
        pre[g] = s2;
      }
      float og = 1.f / (1.f + __expf(-pre[3]));        // early: hides exp latency
      float mn = fmaxf(pre[1] + m_s, pre[0]);
      float ig = __expf(pre[0] - mn);
      float fg = __expf(pre[1] + m_s - mn);
      float e2 = __expf(2.f * pre[2]);
      float th = 1.f - 2.f / (e2 + 1.f);               // tanh(pre[2])
      c_s = fg * c_s + ig * th;
      n_s = fg * n_s + ig;
      m_s = mn;
      float h = og * (c_s / n_s);

      unsigned hu = (unsigned)f2bf(h);
      // publish FIRST (critical path): tagged words, fire-and-forget
      unsigned word = (((unsigned)(tagbase + i) & 0xffffu) << 16) | hu;
      unsigned wa = __shfl(word, (lane * 2) & 63, 64);
      unsigned wb = __shfl(word, (lane * 2 + 1) & 63, 64);
      if (lane < 16 && i < SEQ - 1) {
        u64 v64 = (u64)wa | ((u64)wb << 32);
        __hip_atomic_store(hx + ((long)(b * 2 + (i & 1)) << 9) + (c << 4) + lane,
                           v64, __ATOMIC_RELAXED, __HIP_MEMORY_SCOPE_AGENT);
      }
      // history for amortized hseq dump (off critical path)
      if (lane < 32) hhist[(i >> 5) & 1][i & 31][lane] = (u16)hu;
    } else if (w == 0 && lane < 32 && i + 2 < SEQ) {
      const int g = lane >> 3, o4 = (lane & 7) * 4;
      u64 v = *(const u64*)(xp + ((long)((i + 2) * 8 + b) << 12) + g * 1024 + c * 32 + o4);
      *(u64*)&xpf[(i + 2) & 3][g][o4] = v;
    } else if (w == 6 && lane < 32 && i > 0 && (i & 31) == 0) {
      // dump previous 32-step bank to hseq (plain stores; visible at kernel end)
      const int bank = ((i >> 5) & 1) ^ 1;
#pragma unroll
      for (int j = 0; j < 4; ++j) {
        short8 v = *(const short8*)&hhist[bank][lane][j * 8];
        *(short8*)(hseq + ((long)(b * SEQ + (i - 32 + lane))) * HD + c * 32 + j * 8) = v;
      }
    }
    // single barrier/step: next iteration's phase A starts with its own poll
  }

  // ORDER the final hhist writes (wave 7, step 1023 phase C, after the last
  // barrier) before the epilogue read below. This was R10's correctness bug.
  __syncthreads();

  // epilogue: dump last 32 steps (bank 1 holds steps 992..1023)
  if (w == 6 && lane < 32) {
#pragma unroll
    for (int j = 0; j < 4; ++j) {
      short8 v = *(const short8*)&hhist[1][lane][j * 8];
      *(short8*)(hseq + ((long)(b * SEQ + (SEQ - 32 + lane))) * HD + c * 32 + j * 8) = v;
    }
  }
}

// ---------------- row LayerNorm (D=1024), fp32 out + bf16 copy ----------------
__global__ __launch_bounds__(256, 1) void k_ln(
    const float* __restrict__ z, const float* __restrict__ gamma, const float* __restrict__ beta,
    float* __restrict__ xout, u16* __restrict__ xb)
{
  const int row = blockIdx.x, tid = threadIdx.x;
  const float4 v = *(const float4*)(z + (long)row * HD + tid * 4);
  float s = v.x + v.y + v.z + v.w;
  float s2 = v.x * v.x + v.y * v.y + v.z * v.z + v.w * v.w;
#pragma unroll
  for (int off = 32; off > 0; off >>= 1) {
    s += __shfl_down(s, off, 64);
    s2 += __shfl_down(s2, off, 64);
  }
  __shared__ float red[8];
  const int wid = tid >> 6, lane = tid & 63;
  if (lane == 0) { red[wid] = s; red[4 + wid] = s2; }
  __syncthreads();
  float su = red[0] + red[1] + red[2] + red[3];
  float sq = red[4] + red[5] + red[6] + red[7];
  float mu = su * (1.f / 1024.f);
  float var = sq * (1.f / 1024.f) - mu * mu;
  float rs = rsqrtf(var + 1e-5f);
  const float4 g  = *(const float4*)(gamma + tid * 4);
  const float4 bt = *(const float4*)(beta + tid * 4);
  float4 o;
  o.x = (v.x - mu) * rs * g.x + bt.x;
  o.y = (v.y - mu) * rs * g.y + bt.y;
  o.z = (v.z - mu) * rs * g.z + bt.z;
  o.w = (v.w - mu) * rs * g.w + bt.w;
  *(float4*)(xout + (long)row * HD + tid * 4) = o;
  ushort4 ob;
  ob.x = f2bf(o.x); ob.y = f2bf(o.y); ob.z = f2bf(o.z); ob.w = f2bf(o.w);
  *(ushort4*)(xb + (long)row * HD + tid * 4) = ob;
}

// ---------------- launch ----------------
extern "C" void kernel_launch(void* const* d_in, const int* in_sizes, int n_in,
                              void* d_out, int out_size, void* d_ws, size_t ws_size,
                              hipStream_t stream)
{
  const float* input = (const float*)d_in[0];
  const float* W[2]  = { (const float*)d_in[1], (const float*)d_in[8] };
  const float* R[2]  = { (const float*)d_in[2], (const float*)d_in[9] };
  const float* bb[2] = { (const float*)d_in[3], (const float*)d_in[10] };
  const float* pW[2] = { (const float*)d_in[4], (const float*)d_in[11] };
  const float* pb[2] = { (const float*)d_in[5], (const float*)d_in[12] };
  const float* gm[2] = { (const float*)d_in[6], (const float*)d_in[13] };
  const float* bt[2] = { (const float*)d_in[7], (const float*)d_in[14] };
  float* out = (float*)d_out;

  char* p = (char*)d_ws;
  size_t off = 0;
  auto alloc = [&](size_t bytes) { char* q = p + off; off += (bytes + 255) & ~(size_t)255; return (void*)q; };
  u64* hx = (u64*)alloc(NB * 2 * 512 * 8);             // 64KB tagged h exchange
  u16* xb     = (u16*)alloc((size_t)MROWS * HD * 2);
  u16* Wb[2]  = { (u16*)alloc((size_t)GD * HD * 2), (u16*)alloc((size_t)GD * HD * 2) };
  u16* Rbv[2] = { (u16*)alloc((size_t)GD * HD * 2), (u16*)alloc((size_t)GD * HD * 2) };
  u16* pWb[2] = { (u16*)alloc((size_t)HD * HD * 2), (u16*)alloc((size_t)HD * HD * 2) };
  u16* xpb    = (u16*)alloc((size_t)MROWS * GD * 2);
  u16* hs     = (u16*)alloc((size_t)MROWS * HD * 2);
  float* zb   = (float*)alloc((size_t)MROWS * HD * 4);
  float* x1   = (float*)alloc((size_t)MROWS * HD * 4);

  auto conv = [&](const float* src, u16* dst, long n) {
    int blocks = (int)((n / 4 + 255) / 256); if (blocks > 2048) blocks = 2048;
    k_tobf16<<<dim3(blocks), dim3(256), 0, stream>>>(src, dst, n);
  };
  conv(input, xb, (long)MROWS * HD);
  conv(W[0], Wb[0], (long)GD * HD);  conv(W[1], Wb[1], (long)GD * HD);
  conv(R[0], Rbv[0], (long)GD * HD); conv(R[1], Rbv[1], (long)GD * HD);
  conv(pW[0], pWb[0], (long)HD * HD); conv(pW[1], pWb[1], (long)HD * HD);

  // poison exchange buffer once per launch: 0xAAAA tag never targeted; cross-
  // replay tag aliasing is benign (deterministic replay -> identical values)
  hipMemsetAsync(hx, 0xAA, NB * 2 * 512 * 8, stream);

  for (int l = 0; l < 2; ++l) {
    // xp = x @ W.T + b  -> bf16, t-major layout
    k_gemm<0><<<dim3(GD / 128, MROWS / 128), 256, 0, stream>>>(
        xb, Wb[l], bb[l], nullptr, xpb, nullptr, GD, HD);
    // sLSTM scan: 256 WGs x 512 threads, 8 batch groups of 32
    k_scan<<<dim3(256), dim3(512), 0, stream>>>(xpb, Rbv[l], hs, hx, l * 1024);
    // z = gelu(hseq @ pW.T + pb) + x_res
    const float* resp = (l == 0) ? input : x1;
    k_gemm<1><<<dim3(HD / 128, MROWS / 128), 256, 0, stream>>>(
        hs, pWb[l], pb[l], resp, nullptr, zb, HD, HD);
    // layernorm -> fp32 x_next (+ bf16 copy for next layer's GEMM1)
    float* xo = (l == 0) ? x1 : out;
    k_ln<<<dim3(MROWS), dim3(256), 0, stream>>>(zb, gm[l], bt[l], xo, xb);
  }
}